// Round 12
// baseline (592.292 us; speedup 1.0000x reference)
//
#include <hip/hip_runtime.h>
#include <hip/hip_bf16.h>
#include <math.h>

#define L_SEQ 2048
#define D_MODEL 128
#define N_ROWS 16384  // B*L = 8*2048
#define LOG2E 1.4426950408889634f

typedef __attribute__((ext_vector_type(8))) short bf16x8;
typedef __attribute__((ext_vector_type(4))) short short4v;
typedef __attribute__((ext_vector_type(4))) float f32x4;

__device__ __forceinline__ short f2bf(float x)  // RNE
{
    __hip_bfloat16 b = __float2bfloat16(x);
    return *reinterpret_cast<short*>(&b);
}
__device__ __forceinline__ short f2bf_fast(float x)  // round-half-up, x >= 0
{
    unsigned u = __builtin_bit_cast(unsigned, x);
    return (short)((u + 0x8000u) >> 16);
}
__device__ __forceinline__ float bf2f(short s)
{
    unsigned u = ((unsigned)(unsigned short)s) << 16;
    return __builtin_bit_cast(float, u);
}
__device__ __forceinline__ short f2h(float x)   // v_cvt_f16_f32
{
    _Float16 h = (_Float16)x;
    return (short)__builtin_bit_cast(unsigned short, h);
}
__device__ __forceinline__ float h2f(short s)   // v_cvt_f32_f16
{
    _Float16 h = __builtin_bit_cast(_Float16, (unsigned short)s);
    return (float)h;
}

// ---------------------------------------------------------------------------
// One-shot fp32 -> bf16 conversion of x and all weight matrices.
// ---------------------------------------------------------------------------
__global__ __launch_bounds__(256) void convert_kernel(
    const float* __restrict__ x,    const float* __restrict__ inw,
    const float* __restrict__ ssmi, const float* __restrict__ ssmo,
    const float* __restrict__ qkvw, const float* __restrict__ aow,
    const float* __restrict__ f1w,  const float* __restrict__ f2w,
    short* __restrict__ xb, short* __restrict__ wb)
{
    int it = blockIdx.x * 256 + threadIdx.x;
    const float* src; short* dst; int off;
    if      (it < 131072) { src = x;    dst = xb;          off = it; }
    else if (it < 132096) { src = inw;  dst = wb;          off = it - 131072; }
    else if (it < 140288) { src = ssmi; dst = wb + 8192;   off = it - 132096; }
    else if (it < 144384) { src = ssmo; dst = wb + 73728;  off = it - 140288; }
    else if (it < 156672) { src = qkvw; dst = wb + 106496; off = it - 144384; }
    else if (it < 160768) { src = aow;  dst = wb + 204800; off = it - 156672; }
    else if (it < 177152) { src = f1w;  dst = wb + 237568; off = it - 160768; }
    else                  { src = f2w;  dst = wb + 368640; off = it - 177152; }
    off <<= 3;
    float4 v0 = *(const float4*)(src + off);
    float4 v1 = *(const float4*)(src + off + 4);
    bf16x8 p = {f2bf(v0.x), f2bf(v0.y), f2bf(v0.z), f2bf(v0.w),
                f2bf(v1.x), f2bf(v1.y), f2bf(v1.z), f2bf(v1.w)};
    *(bf16x8*)(dst + off) = p;
}

// ---------------------------------------------------------------------------
// Fused E=128 GEMM + residual + LayerNorm (R10).
// FUSE: 0 = PE+LN, 1 = RES+LN, 2 = RES only (last ff2).
// ---------------------------------------------------------------------------
template <int FUSE>
__global__ __launch_bounds__(256) void gemm_ln(const short* __restrict__ A,
                                               const short* __restrict__ W,
                                               const float* __restrict__ bias,
                                               const float* __restrict__ lnw,
                                               const float* __restrict__ lnb,
                                               float* __restrict__ bh,
                                               short* __restrict__ lnout,
                                               int K)
{
    __shared__ __align__(16) short As[64][72];
    __shared__ __align__(16) short Bs[128][72];

    const int tid  = threadIdx.x;
    const int wave = tid >> 6;
    const int lane = tid & 63;
    const int m    = lane & 15;
    const int quad = lane >> 4;
    const int n0   = blockIdx.x * 64;

    const int arow = tid >> 2, acol = (tid & 3) << 4;
    const int brow = tid >> 1, bcol = (tid & 1) << 5;

    const short* Ap = A + (size_t)(n0 + arow) * K + acol;
    const short* Wp = W + (size_t)brow * K + bcol;

    f32x4 acc[8];
#pragma unroll
    for (int i = 0; i < 8; ++i) acc[i] = (f32x4){0.f, 0.f, 0.f, 0.f};

    bf16x8 a0 = *(const bf16x8*)Ap;
    bf16x8 a1 = *(const bf16x8*)(Ap + 8);
    bf16x8 b0 = *(const bf16x8*)Wp;
    bf16x8 b1 = *(const bf16x8*)(Wp + 8);
    bf16x8 b2 = *(const bf16x8*)(Wp + 16);
    bf16x8 b3 = *(const bf16x8*)(Wp + 24);

    for (int k0 = 0; k0 < K; k0 += 64) {
        *(bf16x8*)&As[arow][acol]      = a0;
        *(bf16x8*)&As[arow][acol + 8]  = a1;
        *(bf16x8*)&Bs[brow][bcol]      = b0;
        *(bf16x8*)&Bs[brow][bcol + 8]  = b1;
        *(bf16x8*)&Bs[brow][bcol + 16] = b2;
        *(bf16x8*)&Bs[brow][bcol + 24] = b3;
        __syncthreads();
        if (k0 + 64 < K) {
            a0 = *(const bf16x8*)(Ap + k0 + 64);
            a1 = *(const bf16x8*)(Ap + k0 + 72);
            b0 = *(const bf16x8*)(Wp + k0 + 64);
            b1 = *(const bf16x8*)(Wp + k0 + 72);
            b2 = *(const bf16x8*)(Wp + k0 + 80);
            b3 = *(const bf16x8*)(Wp + k0 + 88);
        }
#pragma unroll
        for (int ks = 0; ks < 2; ++ks) {
            bf16x8 af = *(const bf16x8*)&As[(wave << 4) + m][(ks << 5) + (quad << 3)];
#pragma unroll
            for (int nt = 0; nt < 8; ++nt) {
                bf16x8 bfr = *(const bf16x8*)&Bs[(nt << 4) + m][(ks << 5) + (quad << 3)];
                acc[nt] = __builtin_amdgcn_mfma_f32_16x16x32_bf16(af, bfr, acc[nt], 0, 0, 0);
            }
        }
        __syncthreads();
    }

    // ---- epilogue: bias (+PE | +res), write fp32 bh, keep v in registers ----
#pragma unroll
    for (int nt = 0; nt < 8; ++nt) {
        int col = (nt << 4) + m;
        float bv = bias[col];
        float fr = 0.f;
        if (FUSE == 0)
            fr = __expf((float)(col & ~1) * (-0.07195578415606394f)); // -ln(1e4)/128
#pragma unroll
        for (int r = 0; r < 4; ++r) {
            int row = n0 + (wave << 4) + (quad << 2) + r;
            float t = acc[nt][r] + bv;
            if (FUSE == 0) {
                float ang = (float)(row & (L_SEQ - 1)) * fr;
                t += (col & 1) ? cosf(ang) : sinf(ang);
            } else {
                t += bh[(size_t)row * 128 + col];
            }
            acc[nt][r] = t;
            bh[(size_t)row * 128 + col] = t;
        }
    }

    if (FUSE < 2) {
        // ---- in-register LayerNorm over the 128 cols of each row ----
        float wv[8], bvn[8];
#pragma unroll
        for (int nt = 0; nt < 8; ++nt) {
            wv[nt]  = lnw[(nt << 4) + m];
            bvn[nt] = lnb[(nt << 4) + m];
        }
#pragma unroll
        for (int r = 0; r < 4; ++r) {
            float s = 0.f;
#pragma unroll
            for (int nt = 0; nt < 8; ++nt) s += acc[nt][r];
            s += __shfl_xor(s, 1);
            s += __shfl_xor(s, 2);
            s += __shfl_xor(s, 4);
            s += __shfl_xor(s, 8);
            float mean = s * (1.f / 128.f);
            float q = 0.f;
#pragma unroll
            for (int nt = 0; nt < 8; ++nt) {
                float d = acc[nt][r] - mean;
                q = fmaf(d, d, q);
            }
            q += __shfl_xor(q, 1);
            q += __shfl_xor(q, 2);
            q += __shfl_xor(q, 4);
            q += __shfl_xor(q, 8);
            float inv = rsqrtf(q * (1.f / 128.f) + 1e-5f);
            int row = n0 + (wave << 4) + (quad << 2) + r;
#pragma unroll
            for (int nt = 0; nt < 8; ++nt) {
                int col = (nt << 4) + m;
                lnout[(size_t)row * 128 + col] =
                    f2bf((acc[nt][r] - mean) * inv * wv[nt] + bvn[nt]);
            }
        }
    }
}

// ---------------------------------------------------------------------------
// bf16-native MFMA GEMM (validated R3-R7). 64x64 tile, BK=64, reg prefetch.
// Remaining epilogues: BF_RELU (ff1), QKV, SCAN_T.
// ---------------------------------------------------------------------------
enum { EPI_BF_RELU = 0, EPI_QKV = 1, EPI_SCAN_T = 2 };

template <int EPI>
__global__ __launch_bounds__(256) void gemm_bf(const short* __restrict__ A,
                                               const short* __restrict__ W,
                                               const float* __restrict__ bias,
                                               short* __restrict__ outb,  // QKV: qs (ks = +2097152); SCAN_T: pt
                                               short* __restrict__ outv,  // QKV: vt
                                               int K, int E)
{
    __shared__ __align__(16) short As[64][72];
    __shared__ __align__(16) short Bs[64][72];

    const int tid  = threadIdx.x;
    const int wave = tid >> 6;
    const int lane = tid & 63;
    const int m    = lane & 15;
    const int quad = lane >> 4;

    const int n0 = blockIdx.y * 64;
    const int e0 = blockIdx.x * 64;

    const int srow = tid >> 2;
    const int scol = (tid & 3) << 4;

    const short* Ap = A + (size_t)(n0 + srow) * K + scol;
    const short* Wp = W + (size_t)(e0 + srow) * K + scol;

    f32x4 acc[4];
#pragma unroll
    for (int i = 0; i < 4; ++i) acc[i] = (f32x4){0.f, 0.f, 0.f, 0.f};

    bf16x8 a0 = *(const bf16x8*)Ap;
    bf16x8 a1 = *(const bf16x8*)(Ap + 8);
    bf16x8 w0 = *(const bf16x8*)Wp;
    bf16x8 w1 = *(const bf16x8*)(Wp + 8);

    for (int k0 = 0; k0 < K; k0 += 64) {
        *(bf16x8*)&As[srow][scol]     = a0;
        *(bf16x8*)&As[srow][scol + 8] = a1;
        *(bf16x8*)&Bs[srow][scol]     = w0;
        *(bf16x8*)&Bs[srow][scol + 8] = w1;
        __syncthreads();
        if (k0 + 64 < K) {  // prefetch next chunk while MFMAs run
            a0 = *(const bf16x8*)(Ap + k0 + 64);
            a1 = *(const bf16x8*)(Ap + k0 + 72);
            w0 = *(const bf16x8*)(Wp + k0 + 64);
            w1 = *(const bf16x8*)(Wp + k0 + 72);
        }
#pragma unroll
        for (int ks = 0; ks < 2; ++ks) {
            bf16x8 af = *(const bf16x8*)&As[(wave << 4) + m][(ks << 5) + (quad << 3)];
#pragma unroll
            for (int nt = 0; nt < 4; ++nt) {
                bf16x8 bfr = *(const bf16x8*)&Bs[(nt << 4) + m][(ks << 5) + (quad << 3)];
                acc[nt] = __builtin_amdgcn_mfma_f32_16x16x32_bf16(af, bfr, acc[nt], 0, 0, 0);
            }
        }
        __syncthreads();
    }

    if (EPI == EPI_QKV) {
        const float QSC = 0.17677669529663687f * LOG2E;  // 1/sqrt(32) * log2e
        if (e0 < 256) {
            short* dst = (e0 < 128) ? outb : (outb + 2097152);
            int cbase = (e0 < 128) ? e0 : (e0 - 128);
#pragma unroll
            for (int nt = 0; nt < 4; ++nt) {
                int col = cbase + (nt << 4) + m;
                float bv = bias[e0 + (nt << 4) + m];
#pragma unroll
                for (int r = 0; r < 4; ++r) {
                    int row = n0 + (wave << 4) + (quad << 2) + r;
                    float v = acc[nt][r] + bv;
                    if (e0 < 128) v *= QSC;
                    dst[(size_t)row * 128 + col] = f2bf(v);
                }
            }
        } else {
            int bb_ = n0 >> 11;
            int l0  = (n0 & (L_SEQ - 1)) + (wave << 4) + (quad << 2);
#pragma unroll
            for (int nt = 0; nt < 4; ++nt) {
                int c  = (e0 - 256) + (nt << 4) + m;
                int hh = c >> 5, dd = c & 31;
                float bv = bias[e0 + (nt << 4) + m];
                short4v pk;
#pragma unroll
                for (int r = 0; r < 4; ++r) pk[r] = f2bf(acc[nt][r] + bv);
                *(short4v*)&outv[(size_t)((bb_ * 4 + hh) * 32 + dd) * L_SEQ + l0] = pk;
            }
        }
    } else if (EPI == EPI_SCAN_T) {
        // transposed write pt[b][e][l] (fp16): u2 for e<128, sigmoid(g) for e>=128
        int bb_ = n0 >> 11;
        int l0  = (n0 & (L_SEQ - 1)) + (wave << 4) + (quad << 2);
#pragma unroll
        for (int nt = 0; nt < 4; ++nt) {
            int col = e0 + (nt << 4) + m;
            float bv = bias[col];
            short4v pk;
            if (e0 < 128) {
#pragma unroll
                for (int r = 0; r < 4; ++r)
                    pk[r] = f2h((acc[nt][r] + bv) * (2.f * LOG2E));
            } else {
#pragma unroll
                for (int r = 0; r < 4; ++r) {
                    float gr = acc[nt][r] + bv;
                    float g = __builtin_amdgcn_rcpf(
                        1.f + __builtin_amdgcn_exp2f(-gr * LOG2E));
                    pk[r] = f2h(g);
                }
            }
            *(short4v*)&outb[(((size_t)(bb_ * 256 + col)) << 11) + l0] = pk;
        }
    } else {  // EPI_BF_RELU
#pragma unroll
        for (int nt = 0; nt < 4; ++nt) {
            int col = e0 + (nt << 4) + m;
            float bv = bias[col];
#pragma unroll
            for (int r = 0; r < 4; ++r) {
                int row = n0 + (wave << 4) + (quad << 2) + r;
                float v = fmaxf(acc[nt][r] + bv, 0.f);
                outb[(size_t)row * E + col] = f2bf(v);
            }
        }
    }
}

// ---------------------------------------------------------------------------
// SSM gated scan v5: ILP=2 retry with the R8 failure fixed.
// R8 post-mortem: __launch_bounds__(64) w/o min-waves let the allocator chase
// a high occupancy tier (VGPR capped ~40) and rematerialize prefetch loads,
// destroying the pipeline. Fixes: (1) __launch_bounds__(64, 1) unlocks the
// full VGPR budget; (2) CH=8 halves the buffer registers (8x bf16x8 = 32).
// Thread t of block b owns chains (b,t) and (b,t+64); 8 blocks x 64 threads.
// Two independent recurrences interleave so the pair completes in ~one chain
// latency (~35-45 cy per effective step vs 80 single-chain).
// ---------------------------------------------------------------------------
__device__ __forceinline__ void scan8_2(float& h0, float& h1,
                                        bf16x8 u80, bf16x8 g80,
                                        bf16x8 u81, bf16x8 g81,
                                        float a20, float a21,
                                        short* __restrict__ ob, int l0)
{
#pragma unroll
    for (int i = 0; i < 8; ++i) {
        // chain 0
        float u20  = h2f(u80[i]);
        float g0   = h2f(g80[i]);
        float omg0 = 1.f - g0;
        float m20  = -2.f * omg0;
        float c00  = fmaf(g0, h0, omg0);
        float e20  = __builtin_amdgcn_exp2f(fmaf(a20, h0, u20));
        // chain 1 (independent — fills chain-0 trans latency)
        float u21  = h2f(u81[i]);
        float g1   = h2f(g81[i]);
        float omg1 = 1.f - g1;
        float m21  = -2.f * omg1;
        float c01  = fmaf(g1, h1, omg1);
        float e21  = __builtin_amdgcn_exp2f(fmaf(a21, h1, u21));
        float r0   = __builtin_amdgcn_rcpf(1.f + e20);
        float r1   = __builtin_amdgcn_rcpf(1.f + e21);
        h0 = fmaf(m20, r0, c00);
        h1 = fmaf(m21, r1, c01);
        ob[(l0 + i) * D_MODEL]      = f2bf(h0);
        ob[(l0 + i) * D_MODEL + 64] = f2bf(h1);
    }
}

__global__ __launch_bounds__(64, 1) void scan_kernel(const short* __restrict__ pt,
                                                     const float* __restrict__ A,
                                                     short* __restrict__ hs)
{
    int b  = blockIdx.x;              // 8 blocks
    int d0 = threadIdx.x;             // chain0: d0, chain1: d0+64
    float a20 = 2.f * A[d0] * LOG2E;
    float a21 = 2.f * A[d0 + 64] * LOG2E;
    const short* up0 = pt + (((size_t)(b * 256 + d0)) << 11);
    const short* gp0 = up0 + (((size_t)128) << 11);
    const short* up1 = up0 + (((size_t)64) << 11);
    const short* gp1 = up1 + (((size_t)128) << 11);
    short* ob = hs + ((size_t)(b << 11)) * D_MODEL + d0;

    bf16x8 uA0 = *(const bf16x8*)up0;
    bf16x8 gA0 = *(const bf16x8*)gp0;
    bf16x8 uA1 = *(const bf16x8*)up1;
    bf16x8 gA1 = *(const bf16x8*)gp1;
    bf16x8 uB0, gB0, uB1, gB1;

    float h0 = 0.f, h1 = 0.f;
    for (int l0 = 0; l0 < L_SEQ; l0 += 16) {
        uB0 = *(const bf16x8*)(up0 + l0 + 8);
        gB0 = *(const bf16x8*)(gp0 + l0 + 8);
        uB1 = *(const bf16x8*)(up1 + l0 + 8);
        gB1 = *(const bf16x8*)(gp1 + l0 + 8);
        scan8_2(h0, h1, uA0, gA0, uA1, gA1, a20, a21, ob, l0);
        if (l0 + 16 < L_SEQ) {
            uA0 = *(const bf16x8*)(up0 + l0 + 16);
            gA0 = *(const bf16x8*)(gp0 + l0 + 16);
            uA1 = *(const bf16x8*)(up1 + l0 + 16);
            gA1 = *(const bf16x8*)(gp1 + l0 + 16);
        }
        scan8_2(h0, h1, uB0, gB0, uB1, gB1, a20, a21, ob, l0 + 8);
    }
}

// ---------------------------------------------------------------------------
// Flash attention v3 (R6): zero-shift softmax, double-buffered K/V,
// register row-sum, 1 barrier/chunk.
// ---------------------------------------------------------------------------
__global__ __launch_bounds__(256) void attn_kernel(const short* __restrict__ Qs,
                                                   const short* __restrict__ Ks,
                                                   const short* __restrict__ Vtg,
                                                   short* __restrict__ outb)
{
    __shared__ __align__(16) short Klds[2][64][40];
    __shared__ __align__(16) short Vlds[2][32][72];
    __shared__ __align__(16) short Plds[4][16][72];

    const int tid  = threadIdx.x;
    const int wave = tid >> 6;
    const int lane = tid & 63;
    const int m    = lane & 15;
    const int quad = lane >> 4;

    const int bid = blockIdx.x;
    const int b  = bid >> 7;
    const int h  = (bid >> 5) & 3;
    const int q0 = (bid & 31) << 6;

    bf16x8 qfrag = *(const bf16x8*)&Qs[((size_t)((b << 11) + q0 + (wave << 4) + m)) * 128
                                       + (h << 5) + (quad << 3)];

    f32x4 O[2];
    O[0] = (f32x4){0.f, 0.f, 0.f, 0.f};
    O[1] = (f32x4){0.f, 0.f, 0.f, 0.f};
    float rs[4] = {0.f, 0.f, 0.f, 0.f};

    const int krow = tid >> 2, dg = (tid & 3) << 3;
    const int vrow = tid >> 3, kg = (tid & 7) << 3;
    const short* kbase = Ks + ((size_t)(b << 11) + krow) * 128 + (h << 5) + dg;
    const short* vbase = Vtg + ((size_t)((b << 2) + h) * 32 + vrow) * L_SEQ + kg;

    // stage chunk 0
    bf16x8 kreg = *(const bf16x8*)kbase;
    bf16x8 vreg = *(const bf16x8*)vbase;
    *(bf16x8*)&Klds[0][krow][dg] = kreg;
    *(bf16x8*)&Vlds[0][vrow][kg] = vreg;
    __syncthreads();

    for (int kc = 0; kc < 32; ++kc) {
        const int cur = kc & 1;
        if (kc < 31) {  // prefetch next chunk into registers
            kreg = *(const bf16x8*)(kbase + (size_t)((kc + 1) << 6) * 128);
            vreg = *(const bf16x8*)(vbase + ((kc + 1) << 6));
        }

        // ---- QK^T: 4 key-tiles ----
        f32x4 S[4];
#pragma unroll
        for (int kt = 0; kt < 4; ++kt) {
            bf16x8 kf = *(const bf16x8*)&Klds[cur][(kt << 4) + m][quad << 3];
            S[kt] = __builtin_amdgcn_mfma_f32_16x16x32_bf16(
                qfrag, kf, (f32x4){0.f, 0.f, 0.f, 0.f}, 0, 0, 0);
        }

        // ---- P = exp2(S); accumulate row-sum in registers; write A-layout ----
#pragma unroll
        for (int kt = 0; kt < 4; ++kt)
#pragma unroll
            for (int r = 0; r < 4; ++r) {
                float p = __builtin_amdgcn_exp2f(S[kt][r]);
                rs[r] += p;
                Plds[wave][(quad << 2) + r][(kt << 4) + m] = f2bf_fast(p);
            }

        // ---- PV (Plds is per-wave: intra-wave lgkmcnt only, no barrier) ----
#pragma unroll
        for (int ktile = 0; ktile < 2; ++ktile) {
            bf16x8 pf = *(const bf16x8*)&Plds[wave][m][(ktile << 5) + (quad << 3)];
#pragma unroll
            for (int dt = 0; dt < 2; ++dt) {
                bf16x8 vf = *(const bf16x8*)&Vlds[cur][(dt << 4) + m][(ktile << 5) + (quad << 3)];
                O[dt] = __builtin_amdgcn_mfma_f32_16x16x32_bf16(pf, vf, O[dt], 0, 0, 0);
            }
        }

        // ---- write next K/V buffer; single barrier per chunk ----
        if (kc < 31) {
            *(bf16x8*)&Klds[cur ^ 1][krow][dg] = kreg;
            *(bf16x8*)&Vlds[cur ^ 1][vrow][kg] = vreg;
        }
        __syncthreads();
    }

    // one-time row-sum reduce across the 16 m-lanes (xor<16 preserves quad)
#pragma unroll
    for (int r = 0; r < 4; ++r) {
        float s = rs[r];
        s += __shfl_xor(s, 1);
        s += __shfl_xor(s, 2);
        s += __shfl_xor(s, 4);
        s += __shfl_xor(s, 8);
        rs[r] = s;
    }

#pragma unroll
    for (int r = 0; r < 4; ++r) {
        float inv = 1.f / rs[r];
        int row = (b << 11) + q0 + (wave << 4) + (quad << 2) + r;
        short* op = outb + (size_t)row * D_MODEL + (h << 5) + m;
        op[0]  = f2bf(O[0][r] * inv);
        op[16] = f2bf(O[1][r] * inv);
    }
}

// ---------------------------------------------------------------------------
// Pooling v2 (R9): 8 blocks x 1024 threads, LDS combine of 8 partials per d.
// ---------------------------------------------------------------------------
__global__ __launch_bounds__(1024) void pool_kernel(const float* __restrict__ h,
                                                    float* __restrict__ pooled)
{
    __shared__ float part[8][128];
    int b   = blockIdx.x;
    int d   = threadIdx.x & 127;
    int seg = threadIdx.x >> 7;    // 0..7
    const float* hb = h + (size_t)b * L_SEQ * D_MODEL;
    float acc = 0.f;
    int l0 = seg << 8;
    for (int l = l0; l < l0 + 256; l += 4) {
        acc += hb[(l + 0) * D_MODEL + d] + hb[(l + 1) * D_MODEL + d]
             + hb[(l + 2) * D_MODEL + d] + hb[(l + 3) * D_MODEL + d];
    }
    part[seg][d] = acc;
    __syncthreads();
    if (threadIdx.x < 128) {
        float s = 0.f;
#pragma unroll
        for (int i = 0; i < 8; ++i) s += part[i][threadIdx.x];
        pooled[b * 128 + threadIdx.x] =
            0.5f * hb[(L_SEQ - 1) * D_MODEL + threadIdx.x] + 0.5f * (s * (1.f / (float)L_SEQ));
    }
}

// ---------------------------------------------------------------------------
// Head: LN -> GELU(Linear 128->128) -> Linear 128->1. One block per batch row.
// ---------------------------------------------------------------------------
__global__ void head_kernel(const float* __restrict__ pooled,
                            const float* __restrict__ hlnw, const float* __restrict__ hlnb,
                            const float* __restrict__ h1w, const float* __restrict__ h1b,
                            const float* __restrict__ h2w, const float* __restrict__ h2b,
                            float* __restrict__ out)
{
    __shared__ float sd[128];
    __shared__ float sq[128];
    int b = blockIdx.x, t = threadIdx.x;
    float v = pooled[b * 128 + t];
    sd[t] = v;
    __syncthreads();
    for (int s = 64; s > 0; s >>= 1) {
        if (t < s) sd[t] += sd[t + s];
        __syncthreads();
    }
    float mu = sd[0] * (1.f / 128.f);
    __syncthreads();
    float dv = v - mu;
    sd[t] = dv * dv;
    __syncthreads();
    for (int s = 64; s > 0; s >>= 1) {
        if (t < s) sd[t] += sd[t + s];
        __syncthreads();
    }
    float var = sd[0] * (1.f / 128.f);
    float q = dv * rsqrtf(var + 1e-5f) * hlnw[t] + hlnb[t];
    __syncthreads();
    sq[t] = q;
    __syncthreads();
    float dot = h1b[t];
    for (int d2 = 0; d2 < 128; ++d2) dot = fmaf(sq[d2], h1w[t * 128 + d2], dot);
    float ge = 0.5f * dot * (1.f + erff(dot * 0.7071067811865475f));
    float term = ge * h2w[t];
    __syncthreads();
    sd[t] = term;
    __syncthreads();
    for (int s = 64; s > 0; s >>= 1) {
        if (t < s) sd[t] += sd[t + s];
        __syncthreads();
    }
    if (t == 0) out[b] = sd[0] + h2b[0];
}

// ---------------------------------------------------------------------------
extern "C" void kernel_launch(void* const* d_in, const int* in_sizes, int n_in,
                              void* d_out, int out_size, void* d_ws, size_t ws_size,
                              hipStream_t stream)
{
    (void)in_sizes; (void)n_in; (void)out_size; (void)ws_size;
    const float* x      = (const float*)d_in[0];
    const float* in_w   = (const float*)d_in[1];
    const float* in_b   = (const float*)d_in[2];
    const float* ssm_nw = (const float*)d_in[3];
    const float* ssm_nb = (const float*)d_in[4];
    const float* ssm_A  = (const float*)d_in[5];
    const float* ssm_iw = (const float*)d_in[6];
    const float* ssm_ib = (const float*)d_in[7];
    const float* ssm_ow = (const float*)d_in[8];
    const float* ssm_ob = (const float*)d_in[9];
    const float* ln1w   = (const float*)d_in[10];
    const float* ln1b   = (const float*)d_in[11];
    const float* ln2w   = (const float*)d_in[12];
    const float* ln2b   = (const float*)d_in[13];
    const float* qkvw   = (const float*)d_in[14];
    const float* qkvb   = (const float*)d_in[15];
    const float* aow    = (const float*)d_in[16];
    const float* aob    = (const float*)d_in[17];
    const float* f1w    = (const float*)d_in[18];
    const float* f1b    = (const float*)d_in[19];
    const float* f2w    = (const float*)d_in[20];
    const float* f2b    = (const float*)d_in[21];
    const float* hlnw   = (const float*)d_in[22];
    const float* hlnb   = (const float*)d_in[23];
    const float* h1w    = (const float*)d_in[24];
    const float* h1b    = (const float*)d_in[25];
    const float* h2w    = (const float*)d_in[26];
    const float* h2b    = (const float*)d_in[27];
    float* out = (float*)d_out;

    char* wsb = (char*)d_ws;
    float* bh     = (float*)(wsb);               // [N,128] fp32 residual stream (8 MB)
    short* abuf   = (short*)(wsb + 8388608);     // [N,512] bf16 wide scratch / scan pt (16 MB)
    short* bbuf   = (short*)(wsb + 25165824);    // [N,128] bf16 ln/hs/attn-out (4 MB)
    short* qs     = (short*)(wsb + 29360128);    // [N,128] bf16 Q prescaled; ks = +2097152
    short* vt     = (short*)(wsb + 37748736);    // [B,4,32,2048] bf16 V^T (4 MB)
    short* xb     = (short*)(wsb + 41943040);    // [N,64] bf16 input (2 MB)
    short* wb     = (short*)(wsb + 44040192);    // bf16 weights (~1 MB)
    float* pooled = (float*)(wsb + 45088768);
    short* ks     = qs + 2097152;

    dim3 blk(256);

    convert_kernel<<<756, blk, 0, stream>>>(x, in_w, ssm_iw, ssm_ow, qkvw, aow, f1w, f2w, xb, wb);

    // input projection + PE + LN(ssm_norm0): writes bh (fp32) and bbuf (bf16 LN)
    gemm_ln<0><<<256, blk, 0, stream>>>(
        xb, wb, in_b, ssm_nw, ssm_nb, bh, bbuf, 64);

    // SSM block 0
    gemm_bf<EPI_SCAN_T><<<dim3(4, 256), blk, 0, stream>>>(
        bbuf, wb + 8192, ssm_ib, abuf, nullptr, 128, 256);
    scan_kernel<<<8, 64, 0, stream>>>(abuf, ssm_A, bbuf);
    gemm_ln<1><<<256, blk, 0, stream>>>(                       // +res, LN(ssm_norm1)
        bbuf, wb + 73728, ssm_ob, ssm_nw + 128, ssm_nb + 128, bh, bbuf, 128);

    // SSM block 1
    gemm_bf<EPI_SCAN_T><<<dim3(4, 256), blk, 0, stream>>>(
        bbuf, wb + 8192 + 32768, ssm_ib + 256, abuf, nullptr, 128, 256);
    scan_kernel<<<8, 64, 0, stream>>>(abuf, ssm_A + 128, bbuf);
    gemm_ln<1><<<256, blk, 0, stream>>>(                       // +res, LN(ln1[0])
        bbuf, wb + 73728 + 16384, ssm_ob + 128, ln1w, ln1b, bh, bbuf, 128);

    // Encoder layer 0
    gemm_bf<EPI_QKV><<<dim3(6, 256), blk, 0, stream>>>(
        bbuf, wb + 106496, qkvb, qs, vt, 128, 384);
    attn_kernel<<<1024, blk, 0, stream>>>(qs, ks, vt, bbuf);
    gemm_ln<1><<<256, blk, 0, stream>>>(                       // +res, LN(ln2[0])
        bbuf, wb + 204800, aob, ln2w, ln2b, bh, bbuf, 128);
    gemm_bf<EPI_BF_RELU><<<dim3(8, 256), blk, 0, stream>>>(
        bbuf, wb + 237568, f1b, abuf, nullptr, 128, 512);
    gemm_ln<1><<<256, blk, 0, stream>>>(                       // ff2[0] +res, LN(ln1[1])
        abuf, wb + 368640, f2b, ln1w + 128, ln1b + 128, bh, bbuf, 512);

    // Encoder layer 1
    gemm_bf<EPI_QKV><<<dim3(6, 256), blk, 0, stream>>>(
        bbuf, wb + 106496 + 49152, qkvb + 384, qs, vt, 128, 384);
    attn_kernel<<<1024, blk, 0, stream>>>(qs, ks, vt, bbuf);
    gemm_ln<1><<<256, blk, 0, stream>>>(                       // +res, LN(ln2[1])
        bbuf, wb + 204800 + 16384, aob + 128, ln2w + 128, ln2b + 128, bh, bbuf, 128);
    gemm_bf<EPI_BF_RELU><<<dim3(8, 256), blk, 0, stream>>>(
        bbuf, wb + 237568 + 65536, f1b + 512, abuf, nullptr, 128, 512);
    gemm_ln<2><<<256, blk, 0, stream>>>(                       // ff2[1] +res only
        abuf, wb + 368640 + 65536, f2b + 128, nullptr, nullptr, bh, nullptr, 512);

    pool_kernel<<<8, 1024, 0, stream>>>(bh, pooled);
    head_kernel<<<8, 128, 0, stream>>>(pooled, hlnw, hlnb, h1w, h1b, h2w, h2b, out);
}

// Round 13
// 469.382 us; speedup vs baseline: 1.2619x; 1.2619x over previous
//
#include <hip/hip_runtime.h>
#include <hip/hip_bf16.h>
#include <math.h>

#define L_SEQ 2048
#define D_MODEL 128
#define N_ROWS 16384  // B*L = 8*2048
#define LOG2E 1.4426950408889634f

typedef __attribute__((ext_vector_type(8))) short bf16x8;
typedef __attribute__((ext_vector_type(4))) short short4v;
typedef __attribute__((ext_vector_type(4))) float f32x4;

__device__ __forceinline__ short f2bf(float x)  // RNE
{
    __hip_bfloat16 b = __float2bfloat16(x);
    return *reinterpret_cast<short*>(&b);
}
__device__ __forceinline__ short f2bf_fast(float x)  // round-half-up, x >= 0
{
    unsigned u = __builtin_bit_cast(unsigned, x);
    return (short)((u + 0x8000u) >> 16);
}
__device__ __forceinline__ float bf2f(short s)
{
    unsigned u = ((unsigned)(unsigned short)s) << 16;
    return __builtin_bit_cast(float, u);
}
__device__ __forceinline__ short f2h(float x)   // v_cvt_f16_f32
{
    _Float16 h = (_Float16)x;
    return (short)__builtin_bit_cast(unsigned short, h);
}
__device__ __forceinline__ float h2f(short s)   // v_cvt_f32_f16
{
    _Float16 h = __builtin_bit_cast(_Float16, (unsigned short)s);
    return (float)h;
}

// ---------------------------------------------------------------------------
// One-shot fp32 -> bf16 conversion of x and all weight matrices.
// ---------------------------------------------------------------------------
__global__ __launch_bounds__(256) void convert_kernel(
    const float* __restrict__ x,    const float* __restrict__ inw,
    const float* __restrict__ ssmi, const float* __restrict__ ssmo,
    const float* __restrict__ qkvw, const float* __restrict__ aow,
    const float* __restrict__ f1w,  const float* __restrict__ f2w,
    short* __restrict__ xb, short* __restrict__ wb)
{
    int it = blockIdx.x * 256 + threadIdx.x;
    const float* src; short* dst; int off;
    if      (it < 131072) { src = x;    dst = xb;          off = it; }
    else if (it < 132096) { src = inw;  dst = wb;          off = it - 131072; }
    else if (it < 140288) { src = ssmi; dst = wb + 8192;   off = it - 132096; }
    else if (it < 144384) { src = ssmo; dst = wb + 73728;  off = it - 140288; }
    else if (it < 156672) { src = qkvw; dst = wb + 106496; off = it - 144384; }
    else if (it < 160768) { src = aow;  dst = wb + 204800; off = it - 156672; }
    else if (it < 177152) { src = f1w;  dst = wb + 237568; off = it - 160768; }
    else                  { src = f2w;  dst = wb + 368640; off = it - 177152; }
    off <<= 3;
    float4 v0 = *(const float4*)(src + off);
    float4 v1 = *(const float4*)(src + off + 4);
    bf16x8 p = {f2bf(v0.x), f2bf(v0.y), f2bf(v0.z), f2bf(v0.w),
                f2bf(v1.x), f2bf(v1.y), f2bf(v1.z), f2bf(v1.w)};
    *(bf16x8*)(dst + off) = p;
}

// ---------------------------------------------------------------------------
// Fused E=128 GEMM + residual + LayerNorm (R10).
// FUSE: 0 = PE+LN, 1 = RES+LN, 2 = RES only (last ff2).
// ---------------------------------------------------------------------------
template <int FUSE>
__global__ __launch_bounds__(256) void gemm_ln(const short* __restrict__ A,
                                               const short* __restrict__ W,
                                               const float* __restrict__ bias,
                                               const float* __restrict__ lnw,
                                               const float* __restrict__ lnb,
                                               float* __restrict__ bh,
                                               short* __restrict__ lnout,
                                               int K)
{
    __shared__ __align__(16) short As[64][72];
    __shared__ __align__(16) short Bs[128][72];

    const int tid  = threadIdx.x;
    const int wave = tid >> 6;
    const int lane = tid & 63;
    const int m    = lane & 15;
    const int quad = lane >> 4;
    const int n0   = blockIdx.x * 64;

    const int arow = tid >> 2, acol = (tid & 3) << 4;
    const int brow = tid >> 1, bcol = (tid & 1) << 5;

    const short* Ap = A + (size_t)(n0 + arow) * K + acol;
    const short* Wp = W + (size_t)brow * K + bcol;

    f32x4 acc[8];
#pragma unroll
    for (int i = 0; i < 8; ++i) acc[i] = (f32x4){0.f, 0.f, 0.f, 0.f};

    bf16x8 a0 = *(const bf16x8*)Ap;
    bf16x8 a1 = *(const bf16x8*)(Ap + 8);
    bf16x8 b0 = *(const bf16x8*)Wp;
    bf16x8 b1 = *(const bf16x8*)(Wp + 8);
    bf16x8 b2 = *(const bf16x8*)(Wp + 16);
    bf16x8 b3 = *(const bf16x8*)(Wp + 24);

    for (int k0 = 0; k0 < K; k0 += 64) {
        *(bf16x8*)&As[arow][acol]      = a0;
        *(bf16x8*)&As[arow][acol + 8]  = a1;
        *(bf16x8*)&Bs[brow][bcol]      = b0;
        *(bf16x8*)&Bs[brow][bcol + 8]  = b1;
        *(bf16x8*)&Bs[brow][bcol + 16] = b2;
        *(bf16x8*)&Bs[brow][bcol + 24] = b3;
        __syncthreads();
        if (k0 + 64 < K) {
            a0 = *(const bf16x8*)(Ap + k0 + 64);
            a1 = *(const bf16x8*)(Ap + k0 + 72);
            b0 = *(const bf16x8*)(Wp + k0 + 64);
            b1 = *(const bf16x8*)(Wp + k0 + 72);
            b2 = *(const bf16x8*)(Wp + k0 + 80);
            b3 = *(const bf16x8*)(Wp + k0 + 88);
        }
#pragma unroll
        for (int ks = 0; ks < 2; ++ks) {
            bf16x8 af = *(const bf16x8*)&As[(wave << 4) + m][(ks << 5) + (quad << 3)];
#pragma unroll
            for (int nt = 0; nt < 8; ++nt) {
                bf16x8 bfr = *(const bf16x8*)&Bs[(nt << 4) + m][(ks << 5) + (quad << 3)];
                acc[nt] = __builtin_amdgcn_mfma_f32_16x16x32_bf16(af, bfr, acc[nt], 0, 0, 0);
            }
        }
        __syncthreads();
    }

    // ---- epilogue: bias (+PE | +res), write fp32 bh, keep v in registers ----
#pragma unroll
    for (int nt = 0; nt < 8; ++nt) {
        int col = (nt << 4) + m;
        float bv = bias[col];
        float fr = 0.f;
        if (FUSE == 0)
            fr = __expf((float)(col & ~1) * (-0.07195578415606394f)); // -ln(1e4)/128
#pragma unroll
        for (int r = 0; r < 4; ++r) {
            int row = n0 + (wave << 4) + (quad << 2) + r;
            float t = acc[nt][r] + bv;
            if (FUSE == 0) {
                float ang = (float)(row & (L_SEQ - 1)) * fr;
                t += (col & 1) ? cosf(ang) : sinf(ang);
            } else {
                t += bh[(size_t)row * 128 + col];
            }
            acc[nt][r] = t;
            bh[(size_t)row * 128 + col] = t;
        }
    }

    if (FUSE < 2) {
        // ---- in-register LayerNorm over the 128 cols of each row ----
        float wv[8], bvn[8];
#pragma unroll
        for (int nt = 0; nt < 8; ++nt) {
            wv[nt]  = lnw[(nt << 4) + m];
            bvn[nt] = lnb[(nt << 4) + m];
        }
#pragma unroll
        for (int r = 0; r < 4; ++r) {
            float s = 0.f;
#pragma unroll
            for (int nt = 0; nt < 8; ++nt) s += acc[nt][r];
            s += __shfl_xor(s, 1);
            s += __shfl_xor(s, 2);
            s += __shfl_xor(s, 4);
            s += __shfl_xor(s, 8);
            float mean = s * (1.f / 128.f);
            float q = 0.f;
#pragma unroll
            for (int nt = 0; nt < 8; ++nt) {
                float d = acc[nt][r] - mean;
                q = fmaf(d, d, q);
            }
            q += __shfl_xor(q, 1);
            q += __shfl_xor(q, 2);
            q += __shfl_xor(q, 4);
            q += __shfl_xor(q, 8);
            float inv = rsqrtf(q * (1.f / 128.f) + 1e-5f);
            int row = n0 + (wave << 4) + (quad << 2) + r;
#pragma unroll
            for (int nt = 0; nt < 8; ++nt) {
                int col = (nt << 4) + m;
                lnout[(size_t)row * 128 + col] =
                    f2bf((acc[nt][r] - mean) * inv * wv[nt] + bvn[nt]);
            }
        }
    }
}

// ---------------------------------------------------------------------------
// bf16-native MFMA GEMM (validated R3-R7). 64x64 tile, BK=64, reg prefetch.
// Remaining epilogues: BF_RELU (ff1), QKV, SCAN_T.
// ---------------------------------------------------------------------------
enum { EPI_BF_RELU = 0, EPI_QKV = 1, EPI_SCAN_T = 2 };

template <int EPI>
__global__ __launch_bounds__(256) void gemm_bf(const short* __restrict__ A,
                                               const short* __restrict__ W,
                                               const float* __restrict__ bias,
                                               short* __restrict__ outb,  // QKV: qs (ks = +2097152); SCAN_T: pt
                                               short* __restrict__ outv,  // QKV: vt
                                               int K, int E)
{
    __shared__ __align__(16) short As[64][72];
    __shared__ __align__(16) short Bs[64][72];

    const int tid  = threadIdx.x;
    const int wave = tid >> 6;
    const int lane = tid & 63;
    const int m    = lane & 15;
    const int quad = lane >> 4;

    const int n0 = blockIdx.y * 64;
    const int e0 = blockIdx.x * 64;

    const int srow = tid >> 2;
    const int scol = (tid & 3) << 4;

    const short* Ap = A + (size_t)(n0 + srow) * K + scol;
    const short* Wp = W + (size_t)(e0 + srow) * K + scol;

    f32x4 acc[4];
#pragma unroll
    for (int i = 0; i < 4; ++i) acc[i] = (f32x4){0.f, 0.f, 0.f, 0.f};

    bf16x8 a0 = *(const bf16x8*)Ap;
    bf16x8 a1 = *(const bf16x8*)(Ap + 8);
    bf16x8 w0 = *(const bf16x8*)Wp;
    bf16x8 w1 = *(const bf16x8*)(Wp + 8);

    for (int k0 = 0; k0 < K; k0 += 64) {
        *(bf16x8*)&As[srow][scol]     = a0;
        *(bf16x8*)&As[srow][scol + 8] = a1;
        *(bf16x8*)&Bs[srow][scol]     = w0;
        *(bf16x8*)&Bs[srow][scol + 8] = w1;
        __syncthreads();
        if (k0 + 64 < K) {  // prefetch next chunk while MFMAs run
            a0 = *(const bf16x8*)(Ap + k0 + 64);
            a1 = *(const bf16x8*)(Ap + k0 + 72);
            w0 = *(const bf16x8*)(Wp + k0 + 64);
            w1 = *(const bf16x8*)(Wp + k0 + 72);
        }
#pragma unroll
        for (int ks = 0; ks < 2; ++ks) {
            bf16x8 af = *(const bf16x8*)&As[(wave << 4) + m][(ks << 5) + (quad << 3)];
#pragma unroll
            for (int nt = 0; nt < 4; ++nt) {
                bf16x8 bfr = *(const bf16x8*)&Bs[(nt << 4) + m][(ks << 5) + (quad << 3)];
                acc[nt] = __builtin_amdgcn_mfma_f32_16x16x32_bf16(af, bfr, acc[nt], 0, 0, 0);
            }
        }
        __syncthreads();
    }

    if (EPI == EPI_QKV) {
        const float QSC = 0.17677669529663687f * LOG2E;  // 1/sqrt(32) * log2e
        if (e0 < 256) {
            short* dst = (e0 < 128) ? outb : (outb + 2097152);
            int cbase = (e0 < 128) ? e0 : (e0 - 128);
#pragma unroll
            for (int nt = 0; nt < 4; ++nt) {
                int col = cbase + (nt << 4) + m;
                float bv = bias[e0 + (nt << 4) + m];
#pragma unroll
                for (int r = 0; r < 4; ++r) {
                    int row = n0 + (wave << 4) + (quad << 2) + r;
                    float v = acc[nt][r] + bv;
                    if (e0 < 128) v *= QSC;
                    dst[(size_t)row * 128 + col] = f2bf(v);
                }
            }
        } else {
            int bb_ = n0 >> 11;
            int l0  = (n0 & (L_SEQ - 1)) + (wave << 4) + (quad << 2);
#pragma unroll
            for (int nt = 0; nt < 4; ++nt) {
                int c  = (e0 - 256) + (nt << 4) + m;
                int hh = c >> 5, dd = c & 31;
                float bv = bias[e0 + (nt << 4) + m];
                short4v pk;
#pragma unroll
                for (int r = 0; r < 4; ++r) pk[r] = f2bf(acc[nt][r] + bv);
                *(short4v*)&outv[(size_t)((bb_ * 4 + hh) * 32 + dd) * L_SEQ + l0] = pk;
            }
        }
    } else if (EPI == EPI_SCAN_T) {
        // transposed write pt[b][e][l] (fp16): u2 for e<128, sigmoid(g) for e>=128
        int bb_ = n0 >> 11;
        int l0  = (n0 & (L_SEQ - 1)) + (wave << 4) + (quad << 2);
#pragma unroll
        for (int nt = 0; nt < 4; ++nt) {
            int col = e0 + (nt << 4) + m;
            float bv = bias[col];
            short4v pk;
            if (e0 < 128) {
#pragma unroll
                for (int r = 0; r < 4; ++r)
                    pk[r] = f2h((acc[nt][r] + bv) * (2.f * LOG2E));
            } else {
#pragma unroll
                for (int r = 0; r < 4; ++r) {
                    float gr = acc[nt][r] + bv;
                    float g = __builtin_amdgcn_rcpf(
                        1.f + __builtin_amdgcn_exp2f(-gr * LOG2E));
                    pk[r] = f2h(g);
                }
            }
            *(short4v*)&outb[(((size_t)(bb_ * 256 + col)) << 11) + l0] = pk;
        }
    } else {  // EPI_BF_RELU
#pragma unroll
        for (int nt = 0; nt < 4; ++nt) {
            int col = e0 + (nt << 4) + m;
            float bv = bias[col];
#pragma unroll
            for (int r = 0; r < 4; ++r) {
                int row = n0 + (wave << 4) + (quad << 2) + r;
                float v = fmaxf(acc[nt][r] + bv, 0.f);
                outb[(size_t)row * E + col] = f2bf(v);
            }
        }
    }
}

// ---------------------------------------------------------------------------
// SSM gated scan — R7/R9 single-chain version, PERMANENT.
// ILP=2 failed twice (R8: VGPR 40, R11: VGPR 24 — allocator rematerializes
// the dual-chain double-buffer, re-serializing the loads). Single chain,
// 16 blocks x 64 threads, fp16 operands from EPI_SCAN_T, 2 trans ops/step.
// Accepted floor: ~68 us/dispatch (trans-pipe + chain latency at 1 wave/SIMD).
// ---------------------------------------------------------------------------
#define SCAN_CH 16

__device__ __forceinline__ void scan8(float& h, bf16x8 u8, bf16x8 g8,
                                      float a2, short* __restrict__ ob, int l0)
{
#pragma unroll
    for (int i = 0; i < 8; ++i) {
        float u2 = h2f(u8[i]);
        float g  = h2f(g8[i]);
        float omg = 1.f - g;
        float m2  = -2.f * omg;
        float c0 = fmaf(g, h, omg);                          // parallel to exp path
        float e2 = __builtin_amdgcn_exp2f(fmaf(a2, h, u2));  // exp(2x)
        float r  = __builtin_amdgcn_rcpf(1.f + e2);
        h = fmaf(m2, r, c0);
        ob[(l0 + i) * D_MODEL] = f2bf(h);
    }
}

__global__ __launch_bounds__(64) void scan_kernel(const short* __restrict__ pt,
                                                  const float* __restrict__ A,
                                                  short* __restrict__ hs)
{
    int blk = blockIdx.x;             // 16 blocks
    int b   = blk >> 1;
    int d   = ((blk & 1) << 6) + threadIdx.x;
    float a2 = 2.f * A[d] * LOG2E;
    const short* up = pt + (((size_t)(b * 256 + d)) << 11);
    const short* gp = up + (((size_t)128) << 11);
    short* ob = hs + ((size_t)(b << 11)) * D_MODEL + d;

    bf16x8 uA0 = *(const bf16x8*)up;
    bf16x8 uA1 = *(const bf16x8*)(up + 8);
    bf16x8 gA0 = *(const bf16x8*)gp;
    bf16x8 gA1 = *(const bf16x8*)(gp + 8);
    bf16x8 uB0, uB1, gB0, gB1;

    float h = 0.f;
    for (int l0 = 0; l0 < L_SEQ; l0 += 2 * SCAN_CH) {
        uB0 = *(const bf16x8*)(up + l0 + 16);
        uB1 = *(const bf16x8*)(up + l0 + 24);
        gB0 = *(const bf16x8*)(gp + l0 + 16);
        gB1 = *(const bf16x8*)(gp + l0 + 24);
        scan8(h, uA0, gA0, a2, ob, l0);
        scan8(h, uA1, gA1, a2, ob, l0 + 8);
        if (l0 + 32 < L_SEQ) {
            uA0 = *(const bf16x8*)(up + l0 + 32);
            uA1 = *(const bf16x8*)(up + l0 + 40);
            gA0 = *(const bf16x8*)(gp + l0 + 32);
            gA1 = *(const bf16x8*)(gp + l0 + 40);
        }
        scan8(h, uB0, gB0, a2, ob, l0 + 16);
        scan8(h, uB1, gB1, a2, ob, l0 + 24);
    }
}

// ---------------------------------------------------------------------------
// Flash attention v3 (R6): zero-shift softmax, double-buffered K/V,
// register row-sum, 1 barrier/chunk.
// ---------------------------------------------------------------------------
__global__ __launch_bounds__(256) void attn_kernel(const short* __restrict__ Qs,
                                                   const short* __restrict__ Ks,
                                                   const short* __restrict__ Vtg,
                                                   short* __restrict__ outb)
{
    __shared__ __align__(16) short Klds[2][64][40];
    __shared__ __align__(16) short Vlds[2][32][72];
    __shared__ __align__(16) short Plds[4][16][72];

    const int tid  = threadIdx.x;
    const int wave = tid >> 6;
    const int lane = tid & 63;
    const int m    = lane & 15;
    const int quad = lane >> 4;

    const int bid = blockIdx.x;
    const int b  = bid >> 7;
    const int h  = (bid >> 5) & 3;
    const int q0 = (bid & 31) << 6;

    bf16x8 qfrag = *(const bf16x8*)&Qs[((size_t)((b << 11) + q0 + (wave << 4) + m)) * 128
                                       + (h << 5) + (quad << 3)];

    f32x4 O[2];
    O[0] = (f32x4){0.f, 0.f, 0.f, 0.f};
    O[1] = (f32x4){0.f, 0.f, 0.f, 0.f};
    float rs[4] = {0.f, 0.f, 0.f, 0.f};

    const int krow = tid >> 2, dg = (tid & 3) << 3;
    const int vrow = tid >> 3, kg = (tid & 7) << 3;
    const short* kbase = Ks + ((size_t)(b << 11) + krow) * 128 + (h << 5) + dg;
    const short* vbase = Vtg + ((size_t)((b << 2) + h) * 32 + vrow) * L_SEQ + kg;

    // stage chunk 0
    bf16x8 kreg = *(const bf16x8*)kbase;
    bf16x8 vreg = *(const bf16x8*)vbase;
    *(bf16x8*)&Klds[0][krow][dg] = kreg;
    *(bf16x8*)&Vlds[0][vrow][kg] = vreg;
    __syncthreads();

    for (int kc = 0; kc < 32; ++kc) {
        const int cur = kc & 1;
        if (kc < 31) {  // prefetch next chunk into registers
            kreg = *(const bf16x8*)(kbase + (size_t)((kc + 1) << 6) * 128);
            vreg = *(const bf16x8*)(vbase + ((kc + 1) << 6));
        }

        // ---- QK^T: 4 key-tiles ----
        f32x4 S[4];
#pragma unroll
        for (int kt = 0; kt < 4; ++kt) {
            bf16x8 kf = *(const bf16x8*)&Klds[cur][(kt << 4) + m][quad << 3];
            S[kt] = __builtin_amdgcn_mfma_f32_16x16x32_bf16(
                qfrag, kf, (f32x4){0.f, 0.f, 0.f, 0.f}, 0, 0, 0);
        }

        // ---- P = exp2(S); accumulate row-sum in registers; write A-layout ----
#pragma unroll
        for (int kt = 0; kt < 4; ++kt)
#pragma unroll
            for (int r = 0; r < 4; ++r) {
                float p = __builtin_amdgcn_exp2f(S[kt][r]);
                rs[r] += p;
                Plds[wave][(quad << 2) + r][(kt << 4) + m] = f2bf_fast(p);
            }

        // ---- PV (Plds is per-wave: intra-wave lgkmcnt only, no barrier) ----
#pragma unroll
        for (int ktile = 0; ktile < 2; ++ktile) {
            bf16x8 pf = *(const bf16x8*)&Plds[wave][m][(ktile << 5) + (quad << 3)];
#pragma unroll
            for (int dt = 0; dt < 2; ++dt) {
                bf16x8 vf = *(const bf16x8*)&Vlds[cur][(dt << 4) + m][(ktile << 5) + (quad << 3)];
                O[dt] = __builtin_amdgcn_mfma_f32_16x16x32_bf16(pf, vf, O[dt], 0, 0, 0);
            }
        }

        // ---- write next K/V buffer; single barrier per chunk ----
        if (kc < 31) {
            *(bf16x8*)&Klds[cur ^ 1][krow][dg] = kreg;
            *(bf16x8*)&Vlds[cur ^ 1][vrow][kg] = vreg;
        }
        __syncthreads();
    }

    // one-time row-sum reduce across the 16 m-lanes (xor<16 preserves quad)
#pragma unroll
    for (int r = 0; r < 4; ++r) {
        float s = rs[r];
        s += __shfl_xor(s, 1);
        s += __shfl_xor(s, 2);
        s += __shfl_xor(s, 4);
        s += __shfl_xor(s, 8);
        rs[r] = s;
    }

#pragma unroll
    for (int r = 0; r < 4; ++r) {
        float inv = 1.f / rs[r];
        int row = (b << 11) + q0 + (wave << 4) + (quad << 2) + r;
        short* op = outb + (size_t)row * D_MODEL + (h << 5) + m;
        op[0]  = f2bf(O[0][r] * inv);
        op[16] = f2bf(O[1][r] * inv);
    }
}

// ---------------------------------------------------------------------------
// Fused pool + head (R12): one 1024-thread block per batch element.
// Phase 1: strided partial sums into LDS (pool). Phase 2: LN -> GELU(h1) ->
// h2 dot, first 128 threads compute, all threads hit the barriers.
// Removes the pooled global round-trip and one dispatch.
// ---------------------------------------------------------------------------
__global__ __launch_bounds__(1024) void pool_head_kernel(
    const float* __restrict__ h,
    const float* __restrict__ hlnw, const float* __restrict__ hlnb,
    const float* __restrict__ h1w, const float* __restrict__ h1b,
    const float* __restrict__ h2w, const float* __restrict__ h2b,
    float* __restrict__ out)
{
    __shared__ float part[8][128];
    __shared__ float sd[128];
    __shared__ float sq[128];

    int b   = blockIdx.x;
    int t   = threadIdx.x;
    int d   = t & 127;
    int seg = t >> 7;    // 0..7
    const float* hb = h + (size_t)b * L_SEQ * D_MODEL;

    // ---- phase 1: pool ----
    float acc = 0.f;
    int l0 = seg << 8;
    for (int l = l0; l < l0 + 256; l += 4) {
        acc += hb[(l + 0) * D_MODEL + d] + hb[(l + 1) * D_MODEL + d]
             + hb[(l + 2) * D_MODEL + d] + hb[(l + 3) * D_MODEL + d];
    }
    part[seg][d] = acc;
    __syncthreads();

    // ---- phase 2: head (threads 0..127 compute; all hit barriers) ----
    float v = 0.f;
    if (t < 128) {
        float s = 0.f;
#pragma unroll
        for (int i = 0; i < 8; ++i) s += part[i][t];
        v = 0.5f * hb[(L_SEQ - 1) * D_MODEL + t] + 0.5f * (s * (1.f / (float)L_SEQ));
        sd[t] = v;
    }
    __syncthreads();
    for (int s = 64; s > 0; s >>= 1) {
        if (t < s) sd[t] += sd[t + s];
        __syncthreads();
    }
    float mu = sd[0] * (1.f / 128.f);
    __syncthreads();
    float dv = v - mu;
    if (t < 128) sd[t] = dv * dv;
    __syncthreads();
    for (int s = 64; s > 0; s >>= 1) {
        if (t < s) sd[t] += sd[t + s];
        __syncthreads();
    }
    float var = sd[0] * (1.f / 128.f);
    __syncthreads();
    if (t < 128) sq[t] = dv * rsqrtf(var + 1e-5f) * hlnw[t] + hlnb[t];
    __syncthreads();
    if (t < 128) {
        float dot = h1b[t];
        for (int d2 = 0; d2 < 128; ++d2) dot = fmaf(sq[d2], h1w[t * 128 + d2], dot);
        float ge = 0.5f * dot * (1.f + erff(dot * 0.7071067811865475f));
        sd[t] = ge * h2w[t];
    }
    __syncthreads();
    for (int s = 64; s > 0; s >>= 1) {
        if (t < s) sd[t] += sd[t + s];
        __syncthreads();
    }
    if (t == 0) out[b] = sd[0] + h2b[0];
}

// ---------------------------------------------------------------------------
extern "C" void kernel_launch(void* const* d_in, const int* in_sizes, int n_in,
                              void* d_out, int out_size, void* d_ws, size_t ws_size,
                              hipStream_t stream)
{
    (void)in_sizes; (void)n_in; (void)out_size; (void)ws_size;
    const float* x      = (const float*)d_in[0];
    const float* in_w   = (const float*)d_in[1];
    const float* in_b   = (const float*)d_in[2];
    const float* ssm_nw = (const float*)d_in[3];
    const float* ssm_nb = (const float*)d_in[4];
    const float* ssm_A  = (const float*)d_in[5];
    const float* ssm_iw = (const float*)d_in[6];
    const float* ssm_ib = (const float*)d_in[7];
    const float* ssm_ow = (const float*)d_in[8];
    const float* ssm_ob = (const float*)d_in[9];
    const float* ln1w   = (const float*)d_in[10];
    const float* ln1b   = (const float*)d_in[11];
    const float* ln2w   = (const float*)d_in[12];
    const float* ln2b   = (const float*)d_in[13];
    const float* qkvw   = (const float*)d_in[14];
    const float* qkvb   = (const float*)d_in[15];
    const float* aow    = (const float*)d_in[16];
    const float* aob    = (const float*)d_in[17];
    const float* f1w    = (const float*)d_in[18];
    const float* f1b    = (const float*)d_in[19];
    const float* f2w    = (const float*)d_in[20];
    const float* f2b    = (const float*)d_in[21];
    const float* hlnw   = (const float*)d_in[22];
    const float* hlnb   = (const float*)d_in[23];
    const float* h1w    = (const float*)d_in[24];
    const float* h1b    = (const float*)d_in[25];
    const float* h2w    = (const float*)d_in[26];
    const float* h2b    = (const float*)d_in[27];
    float* out = (float*)d_out;

    char* wsb = (char*)d_ws;
    float* bh     = (float*)(wsb);               // [N,128] fp32 residual stream (8 MB)
    short* abuf   = (short*)(wsb + 8388608);     // [N,512] bf16 wide scratch / scan pt (16 MB)
    short* bbuf   = (short*)(wsb + 25165824);    // [N,128] bf16 ln/hs/attn-out (4 MB)
    short* qs     = (short*)(wsb + 29360128);    // [N,128] bf16 Q prescaled; ks = +2097152
    short* vt     = (short*)(wsb + 37748736);    // [B,4,32,2048] bf16 V^T (4 MB)
    short* xb     = (short*)(wsb + 41943040);    // [N,64] bf16 input (2 MB)
    short* wb     = (short*)(wsb + 44040192);    // bf16 weights (~1 MB)
    short* ks     = qs + 2097152;

    dim3 blk(256);

    convert_kernel<<<756, blk, 0, stream>>>(x, in_w, ssm_iw, ssm_ow, qkvw, aow, f1w, f2w, xb, wb);

    // input projection + PE + LN(ssm_norm0): writes bh (fp32) and bbuf (bf16 LN)
    gemm_ln<0><<<256, blk, 0, stream>>>(
        xb, wb, in_b, ssm_nw, ssm_nb, bh, bbuf, 64);

    // SSM block 0
    gemm_bf<EPI_SCAN_T><<<dim3(4, 256), blk, 0, stream>>>(
        bbuf, wb + 8192, ssm_ib, abuf, nullptr, 128, 256);
    scan_kernel<<<16, 64, 0, stream>>>(abuf, ssm_A, bbuf);
    gemm_ln<1><<<256, blk, 0, stream>>>(                       // +res, LN(ssm_norm1)
        bbuf, wb + 73728, ssm_ob, ssm_nw + 128, ssm_nb + 128, bh, bbuf, 128);

    // SSM block 1
    gemm_bf<EPI_SCAN_T><<<dim3(4, 256), blk, 0, stream>>>(
        bbuf, wb + 8192 + 32768, ssm_ib + 256, abuf, nullptr, 128, 256);
    scan_kernel<<<16, 64, 0, stream>>>(abuf, ssm_A + 128, bbuf);
    gemm_ln<1><<<256, blk, 0, stream>>>(                       // +res, LN(ln1[0])
        bbuf, wb + 73728 + 16384, ssm_ob + 128, ln1w, ln1b, bh, bbuf, 128);

    // Encoder layer 0
    gemm_bf<EPI_QKV><<<dim3(6, 256), blk, 0, stream>>>(
        bbuf, wb + 106496, qkvb, qs, vt, 128, 384);
    attn_kernel<<<1024, blk, 0, stream>>>(qs, ks, vt, bbuf);
    gemm_ln<1><<<256, blk, 0, stream>>>(                       // +res, LN(ln2[0])
        bbuf, wb + 204800, aob, ln2w, ln2b, bh, bbuf, 128);
    gemm_bf<EPI_BF_RELU><<<dim3(8, 256), blk, 0, stream>>>(
        bbuf, wb + 237568, f1b, abuf, nullptr, 128, 512);
    gemm_ln<1><<<256, blk, 0, stream>>>(                       // ff2[0] +res, LN(ln1[1])
        abuf, wb + 368640, f2b, ln1w + 128, ln1b + 128, bh, bbuf, 512);

    // Encoder layer 1
    gemm_bf<EPI_QKV><<<dim3(6, 256), blk, 0, stream>>>(
        bbuf, wb + 106496 + 49152, qkvb + 384, qs, vt, 128, 384);
    attn_kernel<<<1024, blk, 0, stream>>>(qs, ks, vt, bbuf);
    gemm_ln<1><<<256, blk, 0, stream>>>(                       // +res, LN(ln2[1])
        bbuf, wb + 204800 + 16384, aob + 128, ln2w + 128, ln2b + 128, bh, bbuf, 128);
    gemm_bf<EPI_BF_RELU><<<dim3(8, 256), blk, 0, stream>>>(
        bbuf, wb + 237568 + 65536, f1b + 512, abuf, nullptr, 128, 512);
    gemm_ln<2><<<256, blk, 0, stream>>>(                       // ff2[1] +res only
        abuf, wb + 368640 + 65536, f2b + 128, nullptr, nullptr, bh, nullptr, 512);

    pool_head_kernel<<<8, 1024, 0, stream>>>(bh, hlnw, hlnb, h1w, h1b, h2w, h2b, out);
}